// Round 9
// baseline (770.387 us; speedup 1.0000x reference)
//
#include <hip/hip_runtime.h>
#include <hip/hip_bf16.h>
#include <math.h>

#define LEAKY_SLOPE 0.2f
#define LN_EPS 1e-5f

typedef __attribute__((ext_vector_type(4))) float f32x4;
typedef __attribute__((ext_vector_type(8))) short short8;

__device__ __forceinline__ float leaky_relu(float x) { return x >= 0.f ? x : LEAKY_SLOPE * x; }
__device__ __forceinline__ float elu1(float x) { return x > 0.f ? x : expm1f(x); }
__device__ __forceinline__ short f2bf(float f) {
    union { __hip_bfloat16 b; short s; } u;
    u.b = __float2bfloat16(f);
    return u.s;
}
__device__ __forceinline__ float bflo(unsigned u) { union { unsigned i; float f; } x; x.i = u << 16; return x.f; }
__device__ __forceinline__ float bfhi(unsigned u) { union { unsigned i; float f; } x; x.i = u & 0xffff0000u; return x.f; }
__device__ __forceinline__ float sbf(short s) { union { unsigned i; float f; } x; x.i = ((unsigned)(unsigned short)s) << 16; return x.f; }
// monotone float<->uint key for atomicMax on floats
__device__ __forceinline__ unsigned fkey(float f) {
    unsigned b = __float_as_uint(f);
    return b ^ (unsigned)(((int)b >> 31) | 0x80000000);
}
__device__ __forceinline__ float funkey(unsigned k) {
    unsigned b = (k & 0x80000000u) ? (k ^ 0x80000000u) : ~k;
    return __uint_as_float(b);
}

// ---------------------------------------------------------------------------
// Per-block int64-vs-int32 edge layout detection (first 64 high words).
#define DETECT_IS64(ei, E)                                              \
    __shared__ int s_is64;                                              \
    {                                                                   \
        if (threadIdx.x < 64) {                                         \
            int v = (threadIdx.x < (E)) ? ((const int*)(ei))[2 * threadIdx.x + 1] : 0; \
            unsigned long long b = __ballot(v != 0);                    \
            if (threadIdx.x == 0) s_is64 = (b == 0ULL);                 \
        }                                                               \
        __syncthreads();                                                \
    }

// ---------------------------------------------------------------------------
// K1 (fat): blocks [0,nbG): h1 = bf16(x @ W1) + fused att scalars + amax.
//           blocks [nbG,nbG+DEGB): in-degree histogram; block nbG also builds
//           rwb (resW bf16 frag table, 8KB) and w2t (W2^T bf16, 16KB).
#define SUBW1 130
#define DEGB 512
__global__ __launch_bounds__(256) void k_fat1(
    const float* __restrict__ x, const float* __restrict__ W1,
    const float* __restrict__ att_s, const float* __restrict__ att_d,
    short* __restrict__ h1, float* __restrict__ a_src, float* __restrict__ a_dst,
    unsigned* __restrict__ amax, int N,
    const void* __restrict__ ei, int E, int* __restrict__ deg,
    const float* __restrict__ resW, short* __restrict__ rwb,
    const float* __restrict__ W2, short* __restrict__ w2t, int nbG)
{
    if ((int)blockIdx.x >= nbG) {
        const int b0 = (int)blockIdx.x - nbG;
        if (b0 == 0) {
            // resW -> bf16 fragment table
            for (int idx = threadIdx.x; idx < 4096; idx += 256) {
                int f = idx >> 9, lane = (idx >> 3) & 63, j = idx & 7;
                int kk = f >> 2, nc = f & 3;
                int k = kk * 32 + (lane >> 4) * 8 + j;
                int col = nc * 16 + (lane & 15);
                rwb[idx] = f2bf(resW[k * 64 + col]);
            }
            // W2^T bf16: w2t[l*128 + k] = bf16(W2[k*64 + l])
            for (int idx = threadIdx.x; idx < 8192; idx += 256) {
                int l = idx >> 7, k = idx & 127;
                w2t[idx] = f2bf(W2[k * 64 + l]);
            }
        }
        DETECT_IS64(ei, E)
        const int is64 = s_is64;
        for (int e = b0 * 256 + threadIdx.x; e < E; e += DEGB * 256) {
            int d = is64 ? (int)((const long long*)ei)[(size_t)E + e] : ((const int*)ei)[(size_t)E + e];
            atomicAdd(&deg[d], 1);
        }
        return;
    }
    __shared__ short WT[16 * SUBW1 * 8];
    __shared__ float sb[64 * 4];  // per-node {s_h0, s_h1, d_h0, d_h1}
    __shared__ float wm[8];
    const int t = threadIdx.x;
    const int w = t >> 6, l = t & 63, lr = l & 15, lk = l >> 4;
    const int n0 = blockIdx.x * 64;
    for (int idx = t; idx < 16384; idx += 256) {
        int k = idx >> 7, col = idx & 127;
        WT[((k >> 3) * SUBW1 + col) * 8 + (k & 7)] = f2bf(W1[idx]);
    }
    sb[t] = 0.f;
    __syncthreads();

    f32x4 acc[4][2];
    #pragma unroll
    for (int mt = 0; mt < 4; ++mt)
        #pragma unroll
        for (int nt = 0; nt < 2; ++nt) acc[mt][nt] = (f32x4){0.f, 0.f, 0.f, 0.f};

    #pragma unroll
    for (int ks = 0; ks < 4; ++ks) {
        short8 bfr[2];
        #pragma unroll
        for (int nt = 0; nt < 2; ++nt) {
            int col = w * 32 + nt * 16 + lr;
            int kk = ks * 4 + lk;
            bfr[nt] = *(const short8*)&WT[(kk * SUBW1 + col) * 8];
        }
        #pragma unroll
        for (int mt = 0; mt < 4; ++mt) {
            int row = n0 + mt * 16 + lr; if (row >= N) row = N - 1;
            const float* ap = x + (size_t)row * 128 + ks * 32 + lk * 8;
            float4 u0 = *(const float4*)ap;
            float4 u1 = *(const float4*)(ap + 4);
            short8 af;
            af[0] = f2bf(u0.x); af[1] = f2bf(u0.y); af[2] = f2bf(u0.z); af[3] = f2bf(u0.w);
            af[4] = f2bf(u1.x); af[5] = f2bf(u1.y); af[6] = f2bf(u1.z); af[7] = f2bf(u1.w);
            acc[mt][0] = __builtin_amdgcn_mfma_f32_16x16x32_bf16(af, bfr[0], acc[mt][0], 0, 0, 0);
            acc[mt][1] = __builtin_amdgcn_mfma_f32_16x16x32_bf16(af, bfr[1], acc[mt][1], 0, 0, 0);
        }
    }

    const int head = w >> 1;
    float asv[2], adv[2];
    #pragma unroll
    for (int nt = 0; nt < 2; ++nt) {
        int ci = (w & 1) * 32 + nt * 16 + lr;
        asv[nt] = att_s[head * 64 + ci];
        adv[nt] = att_d[head * 64 + ci];
    }
    #pragma unroll
    for (int mt = 0; mt < 4; ++mt) {
        #pragma unroll
        for (int i = 0; i < 4; ++i) {
            float ps = acc[mt][0][i] * asv[0] + acc[mt][1][i] * asv[1];
            float pd = acc[mt][0][i] * adv[0] + acc[mt][1][i] * adv[1];
            #pragma unroll
            for (int o = 1; o < 16; o <<= 1) { ps += __shfl_xor(ps, o); pd += __shfl_xor(pd, o); }
            int rl = mt * 16 + lk * 4 + i;
            if (lr == 0) {
                atomicAdd(&sb[rl * 4 + head], ps);
                atomicAdd(&sb[rl * 4 + 2 + head], pd);
            }
            int row = n0 + rl;
            if (row < N) {
                h1[(size_t)row * 128 + w * 32 + lr]      = f2bf(acc[mt][0][i]);
                h1[(size_t)row * 128 + w * 32 + 16 + lr] = f2bf(acc[mt][1][i]);
            }
        }
    }
    __syncthreads();
    int nl = t >> 2, q = t & 3, n = n0 + nl;
    float v = sb[t];
    bool ok = (n < N);
    if (ok) {
        if (q == 0) a_src[n * 2 + 0] = v;
        else if (q == 1) a_src[n * 2 + 1] = v;
        else if (q == 2) a_dst[n * 2 + 0] = v;
        else a_dst[n * 2 + 1] = v;
    }
    float m0 = (ok && q == 0) ? v : -1e30f;
    float m1 = (ok && q == 1) ? v : -1e30f;
    #pragma unroll
    for (int o = 32; o; o >>= 1) { m0 = fmaxf(m0, __shfl_xor(m0, o)); m1 = fmaxf(m1, __shfl_xor(m1, o)); }
    if (l == 0) { wm[w] = m0; wm[4 + w] = m1; }
    __syncthreads();
    if (t == 0) {
        float M0 = fmaxf(fmaxf(wm[0], wm[1]), fmaxf(wm[2], wm[3]));
        float M1 = fmaxf(fmaxf(wm[4], wm[5]), fmaxf(wm[6], wm[7]));
        atomicMax(&amax[0], fkey(M0));
        atomicMax(&amax[1], fkey(M1));
    }
}

// K3a: per-1024-chunk sums.
__global__ __launch_bounds__(256) void k_bsum(const int* __restrict__ deg, int* __restrict__ bsum, int n)
{
    __shared__ int ws[4];
    const int base = blockIdx.x * 1024;
    int s = 0;
    for (int j = threadIdx.x; j < 1024; j += 256) {
        int i = base + j;
        s += (i < n) ? deg[i] : 0;
    }
    #pragma unroll
    for (int o = 32; o; o >>= 1) s += __shfl_down(s, o);
    if ((threadIdx.x & 63) == 0) ws[threadIdx.x >> 6] = s;
    __syncthreads();
    if (threadIdx.x == 0) bsum[blockIdx.x] = ws[0] + ws[1] + ws[2] + ws[3];
}

// K3c: chunk-base (wave-0 sum of bsum[0..bid)) + local scan -> offs, cursor.
__global__ __launch_bounds__(1024) void k_scan3(const int* __restrict__ deg, const int* __restrict__ bsum,
                                                int* __restrict__ offs, int* __restrict__ cursor,
                                                int n, int nb)
{
    __shared__ int ws[16];
    __shared__ int bb;
    const int i = blockIdx.x * 1024 + threadIdx.x;
    const int l = threadIdx.x & 63, w = threadIdx.x >> 6;
    if (threadIdx.x < 64) {
        int v = 0;
        for (int b = l; b < (int)blockIdx.x; b += 64) v += (b < nb) ? bsum[b] : 0;
        #pragma unroll
        for (int o = 32; o; o >>= 1) v += __shfl_xor(v, o);
        if (l == 0) bb = v;
    }
    int v = (i < n) ? deg[i] : 0;
    int x = v;
    #pragma unroll
    for (int o = 1; o < 64; o <<= 1) { int y = __shfl_up(x, o); if (l >= o) x += y; }
    if (l == 63) ws[w] = x;
    __syncthreads();
    if (threadIdx.x < 16) {
        int s = ws[threadIdx.x];
        #pragma unroll
        for (int o = 1; o < 16; o <<= 1) { int y = __shfl_up(s, o); if (threadIdx.x >= o) s += y; }
        ws[threadIdx.x] = s;
    }
    __syncthreads();
    int add = (w ? ws[w - 1] : 0) + bb;
    if (i < n) {
        offs[i + 1] = x + add;
        cursor[i] = x + add - v;
    }
    if (blockIdx.x == 0 && threadIdx.x == 0) offs[0] = 0;
}

// K4: scatter edges into CSR (by destination).
__global__ __launch_bounds__(256) void k_scatter(const void* __restrict__ ei, int E,
                                                 int* __restrict__ cursor, int* __restrict__ csr_src)
{
    DETECT_IS64(ei, E)
    const int is64 = s_is64;
    for (int e = blockIdx.x * blockDim.x + threadIdx.x; e < E; e += gridDim.x * blockDim.x) {
        int s, d;
        if (is64) {
            const long long* p = (const long long*)ei;
            s = (int)p[e]; d = (int)p[(size_t)E + e];
        } else {
            const int* p = (const int*)ei;
            s = p[e]; d = p[(size_t)E + e];
        }
        int pos = atomicAdd(&cursor[d], 1);
        csr_src[pos] = s;
    }
}

// ---------------------------------------------------------------------------
// K5: layer-1 single-pass softmax+gather; same wave then (a) streams its
// node's res-GEMM to out's right half, (b) computes h2[n] = h1a_row @ W2
// in-register (shuffle-broadcast matvec) + layer-2 att scalars + amax2.
// h1a never touches global memory.
__global__ __launch_bounds__(256) void k_layer1(
    const short* __restrict__ h1, const float* __restrict__ a_s, const float* __restrict__ a_d,
    const int* __restrict__ offs, const int* __restrict__ csr,
    const float* __restrict__ b1, const unsigned* __restrict__ amax, int N,
    const float* __restrict__ res, const short* __restrict__ rwb,
    const float* __restrict__ resb, float* __restrict__ out,
    const short* __restrict__ w2t, const float* __restrict__ att_s2, const float* __restrict__ att_d2,
    short* __restrict__ h2, float* __restrict__ a_s2, float* __restrict__ a_d2,
    unsigned* __restrict__ amax2)
{
    const int w = threadIdx.x >> 6, l = threadIdx.x & 63;
    const int n = blockIdx.x * 4 + w;
    if (n >= N) return;
    const float2 adp = *(const float2*)&a_d[2 * n];
    const float2 asp = *(const float2*)&a_s[2 * n];
    const float C0 = leaky_relu(funkey(amax[0]) + adp.x);
    const float C1 = leaky_relu(funkey(amax[1]) + adp.y);
    const float es0 = leaky_relu(asp.x + adp.x) - C0;
    const float es1 = leaky_relu(asp.y + adp.y) - C1;
    const int hsel = l >> 5;
    const int o0 = offs[n], o1 = offs[n + 1];

    float den0 = 0.f, den1 = 0.f;
    float cl0 = 0.f, ch0 = 0.f, cl1 = 0.f, ch1 = 0.f;
    float cl2 = 0.f, ch2 = 0.f, cl3 = 0.f, ch3 = 0.f;
    for (int base = o0; base < o1; base += 64) {
        const int cnt = min(64, o1 - base);
        int sidx = 0; float p0 = 0.f, p1 = 0.f;
        if (l < cnt) {
            sidx = csr[base + l];
            float2 av = *(const float2*)&a_s[2 * sidx];
            p0 = __expf(leaky_relu(av.x + adp.x) - C0);
            p1 = __expf(leaky_relu(av.y + adp.y) - C1);
        }
        den0 += p0; den1 += p1;
        int j = 0;
        for (; j + 4 <= cnt; j += 4) {
            int s0 = __shfl(sidx, j),     s1 = __shfl(sidx, j + 1);
            int s2 = __shfl(sidx, j + 2), s3 = __shfl(sidx, j + 3);
            float q00 = __shfl(p0, j),     q10 = __shfl(p1, j);
            float q01 = __shfl(p0, j + 1), q11 = __shfl(p1, j + 1);
            float q02 = __shfl(p0, j + 2), q12 = __shfl(p1, j + 2);
            float q03 = __shfl(p0, j + 3), q13 = __shfl(p1, j + 3);
            unsigned u0 = *(const unsigned*)(h1 + (size_t)s0 * 128 + 2 * l);
            unsigned u1 = *(const unsigned*)(h1 + (size_t)s1 * 128 + 2 * l);
            unsigned u2 = *(const unsigned*)(h1 + (size_t)s2 * 128 + 2 * l);
            unsigned u3 = *(const unsigned*)(h1 + (size_t)s3 * 128 + 2 * l);
            float w0 = hsel ? q10 : q00, w1 = hsel ? q11 : q01;
            float w2 = hsel ? q12 : q02, w3 = hsel ? q13 : q03;
            cl0 += w0 * bflo(u0); ch0 += w0 * bfhi(u0);
            cl1 += w1 * bflo(u1); ch1 += w1 * bfhi(u1);
            cl2 += w2 * bflo(u2); ch2 += w2 * bfhi(u2);
            cl3 += w3 * bflo(u3); ch3 += w3 * bfhi(u3);
        }
        for (; j < cnt; ++j) {
            int sa = __shfl(sidx, j);
            float qa0 = __shfl(p0, j), qa1 = __shfl(p1, j);
            unsigned ua = *(const unsigned*)(h1 + (size_t)sa * 128 + 2 * l);
            float wa = hsel ? qa1 : qa0;
            cl0 += wa * bflo(ua); ch0 += wa * bfhi(ua);
        }
    }
    #pragma unroll
    for (int o = 32; o; o >>= 1) { den0 += __shfl_xor(den0, o); den1 += __shfl_xor(den1, o); }
    const float psf0 = __expf(es0), psf1 = __expf(es1);
    const float inv0 = 1.f / (den0 + psf0), inv1 = 1.f / (den1 + psf1);

    unsigned us = *(const unsigned*)(h1 + (size_t)n * 128 + 2 * l);
    const float psf = hsel ? psf1 : psf0;
    float acc0 = cl0 + cl1 + cl2 + cl3 + psf * bflo(us);
    float acc1 = ch0 + ch1 + ch2 + ch3 + psf * bfhi(us);
    const float invh = hsel ? inv1 : inv0;
    float2 bv = *(const float2*)&b1[2 * l];
    const float v0 = elu1(acc0 * invh + bv.x);   // h1a channel 2l
    const float v1 = elu1(acc1 * invh + bv.y);   // h1a channel 2l+1

    __builtin_amdgcn_sched_barrier(0);
    const int lr = l & 15, lk = l >> 4;
    // ---- issue res loads early (HBM latency hides under the h2 matvec) ----
    const float* rp = res + (size_t)n * 1024 + lr * 64 + lk * 8;
    const f32x4 f0 = __builtin_nontemporal_load((const f32x4*)(rp));
    const f32x4 f1 = __builtin_nontemporal_load((const f32x4*)(rp + 4));
    const f32x4 f2 = __builtin_nontemporal_load((const f32x4*)(rp + 32));
    const f32x4 f3 = __builtin_nontemporal_load((const f32x4*)(rp + 36));

    // ---- h2[n][l] = sum_k h1a_row[k] * W2[k][l] (shuffle-broadcast matvec) ----
    {
        float h2v = 0.f;
        #pragma unroll
        for (int j = 0; j < 16; ++j) {
            short8 w8 = *(const short8*)(w2t + l * 128 + j * 8);
            #pragma unroll
            for (int m = 0; m < 4; ++m) {
                float h0 = __shfl(v0, 4 * j + m);
                float h1v = __shfl(v1, 4 * j + m);
                h2v += h0 * sbf(w8[2 * m]) + h1v * sbf(w8[2 * m + 1]);
            }
        }
        h2[(size_t)n * 64 + l] = f2bf(h2v);
        float ps = h2v * att_s2[l];
        float pd = h2v * att_d2[l];
        #pragma unroll
        for (int o = 32; o; o >>= 1) { ps += __shfl_xor(ps, o); pd += __shfl_xor(pd, o); }
        if (l == 0) {
            a_s2[n] = ps;
            a_d2[n] = pd;
            atomicMax(&amax2[0], fkey(ps));   // no-return, pipelined
        }
    }

    // ---- this node's res_emb = elu(res @ resW + resb) -> out right half ----
    {
        short8 fa0, fa1;
        fa0[0] = f2bf(f0[0]); fa0[1] = f2bf(f0[1]); fa0[2] = f2bf(f0[2]); fa0[3] = f2bf(f0[3]);
        fa0[4] = f2bf(f1[0]); fa0[5] = f2bf(f1[1]); fa0[6] = f2bf(f1[2]); fa0[7] = f2bf(f1[3]);
        fa1[0] = f2bf(f2[0]); fa1[1] = f2bf(f2[1]); fa1[2] = f2bf(f2[2]); fa1[3] = f2bf(f2[3]);
        fa1[4] = f2bf(f3[0]); fa1[5] = f2bf(f3[1]); fa1[6] = f2bf(f3[2]); fa1[7] = f2bf(f3[3]);
        const short8* rw8 = (const short8*)rwb;
        float* ob = out + (size_t)n * 2048;
        #pragma unroll
        for (int nc = 0; nc < 4; ++nc) {
            f32x4 a = (f32x4){0.f, 0.f, 0.f, 0.f};
            a = __builtin_amdgcn_mfma_f32_16x16x32_bf16(fa0, rw8[nc * 64 + l], a, 0, 0, 0);
            a = __builtin_amdgcn_mfma_f32_16x16x32_bf16(fa1, rw8[(4 + nc) * 64 + l], a, 0, 0, 0);
            const float rb = resb[nc * 16 + lr];
            #pragma unroll
            for (int ii = 0; ii < 4; ++ii)
                __builtin_nontemporal_store(elu1(a[ii] + rb), ob + (lk * 4 + ii) * 128 + 64 + nc * 16 + lr);
        }
    }
}

// ---------------------------------------------------------------------------
// K7: layer-2 single-pass softmax+gather + bias + LayerNorm + broadcast write
// of out's LEFT half. One wave per node.
__global__ __launch_bounds__(256) void k_tail(
    const short* __restrict__ h2, const float* __restrict__ a_s, const float* __restrict__ a_d,
    const int* __restrict__ offs, const int* __restrict__ csr,
    const float* __restrict__ b2, const float* __restrict__ lnw, const float* __restrict__ lnb,
    const unsigned* __restrict__ amax, float* __restrict__ out, int N)
{
    const int w = threadIdx.x >> 6, l = threadIdx.x & 63;
    const int lr = l & 15, lk = l >> 4;
    const int n = blockIdx.x * 4 + w;
    if (n >= N) return;
    const float b2l = b2[l], lnwl = lnw[l], lnbl = lnb[l];
    const float Am = funkey(amax[0]);

    const float adv = a_d[n];
    const float C = leaky_relu(Am + adv);
    const float es = leaky_relu(a_s[n] + adv) - C;
    const int o0 = offs[n], o1 = offs[n + 1];
    float den = 0.f, a0 = 0.f, a1 = 0.f, a2 = 0.f, a3 = 0.f;
    for (int base = o0; base < o1; base += 64) {
        const int cnt = min(64, o1 - base);
        int sidx = 0; float pv = 0.f;
        if (l < cnt) {
            sidx = csr[base + l];
            pv = __expf(leaky_relu(a_s[sidx] + adv) - C);
        }
        den += pv;
        int j = 0;
        for (; j + 4 <= cnt; j += 4) {
            int s0 = __shfl(sidx, j),     s1 = __shfl(sidx, j + 1);
            int s2 = __shfl(sidx, j + 2), s3 = __shfl(sidx, j + 3);
            float q0 = __shfl(pv, j),     q1 = __shfl(pv, j + 1);
            float q2 = __shfl(pv, j + 2), q3 = __shfl(pv, j + 3);
            a0 += q0 * sbf(h2[(size_t)s0 * 64 + l]);
            a1 += q1 * sbf(h2[(size_t)s1 * 64 + l]);
            a2 += q2 * sbf(h2[(size_t)s2 * 64 + l]);
            a3 += q3 * sbf(h2[(size_t)s3 * 64 + l]);
        }
        for (; j < cnt; ++j) {
            int sa = __shfl(sidx, j);
            float qa = __shfl(pv, j);
            a0 += qa * sbf(h2[(size_t)sa * 64 + l]);
        }
    }
    #pragma unroll
    for (int o = 32; o; o >>= 1) den += __shfl_xor(den, o);
    const float psf = __expf(es);
    const float inv = 1.f / (den + psf);
    float o = (a0 + a1 + a2 + a3 + psf * sbf(h2[(size_t)n * 64 + l])) * inv + b2l;
    // ---- LayerNorm across 64 lanes ----
    float mu = o;
    #pragma unroll
    for (int off = 32; off; off >>= 1) mu += __shfl_xor(mu, off);
    mu *= (1.f / 64.f);
    float d = o - mu;
    float vv = d * d;
    #pragma unroll
    for (int off = 32; off; off >>= 1) vv += __shfl_xor(vv, off);
    vv *= (1.f / 64.f);
    const float hl = d * rsqrtf(vv + LN_EPS) * lnwl + lnbl;
    f32x4 hv;
    #pragma unroll
    for (int j = 0; j < 4; ++j) hv[j] = __shfl(hl, lr * 4 + j);
    float* ob = out + (size_t)n * 2048;
    #pragma unroll
    for (int ii = 0; ii < 4; ++ii)
        __builtin_nontemporal_store(hv, (f32x4*)(ob + (lk + 4 * ii) * 128 + lr * 4));
}

// ---------------------------------------------------------------------------
extern "C" void kernel_launch(void* const* d_in, const int* in_sizes, int n_in,
                              void* d_out, int out_size, void* d_ws, size_t ws_size,
                              hipStream_t stream)
{
    const float* x   = (const float*)d_in[0];
    const void*  ei  = d_in[1];
    const float* res = (const float*)d_in[2];
    const float* W1  = (const float*)d_in[3];
    const float* as1 = (const float*)d_in[4];
    const float* ad1 = (const float*)d_in[5];
    const float* b1  = (const float*)d_in[6];
    const float* W2  = (const float*)d_in[7];
    const float* as2 = (const float*)d_in[8];
    const float* ad2 = (const float*)d_in[9];
    const float* b2  = (const float*)d_in[10];
    const float* lnw = (const float*)d_in[11];
    const float* lnb = (const float*)d_in[12];
    const float* rW  = (const float*)d_in[13];
    const float* rb  = (const float*)d_in[14];
    float* out = (float*)d_out;

    const int N = in_sizes[0] / 128;
    const int E = in_sizes[1] / 2;
    const int nb = (N + 1023) / 1024;
    const int nbG = (N + 63) / 64;

    char* base = (char*)d_ws;
    size_t off = 0;
    auto alloc = [&](size_t bytes) -> void* {
        void* p = base + off;
        off = (off + bytes + 255) & ~(size_t)255;
        return p;
    };
    short* h1    = (short*)alloc((size_t)N * 128 * 2);
    short* h2    = (short*)alloc((size_t)N * 64 * 2);
    float* a_s1  = (float*)alloc((size_t)N * 2 * 4);
    float* a_d1  = (float*)alloc((size_t)N * 2 * 4);
    float* a_s2  = (float*)alloc((size_t)N * 4);
    float* a_d2  = (float*)alloc((size_t)N * 4);
    int* deg     = (int*)alloc((size_t)(N + 8) * 4);   // + amax slots
    int* offs    = (int*)alloc((size_t)(N + 1) * 4);
    int* cursor  = (int*)alloc((size_t)N * 4);
    int* csr_src = (int*)alloc((size_t)E * 4);
    int* bsum    = (int*)alloc((size_t)nb * 4);
    short* rwb   = (short*)alloc(4096 * 2);            // resW bf16 fragment table
    short* w2t   = (short*)alloc(8192 * 2);            // W2^T bf16 table
    unsigned* amax1 = (unsigned*)(deg + N);      // 2 slots (heads)
    unsigned* amax2 = (unsigned*)(deg + N + 2);  // 1 slot

    (void)hipMemsetAsync(deg, 0, (size_t)(N + 8) * 4, stream);
    k_fat1<<<nbG + DEGB, 256, 0, stream>>>(x, W1, as1, ad1, h1, a_s1, a_d1, amax1, N,
                                           ei, E, deg, rW, rwb, W2, w2t, nbG);
    k_bsum<<<nb, 256, 0, stream>>>(deg, bsum, N);
    k_scan3<<<nb, 1024, 0, stream>>>(deg, bsum, offs, cursor, N, nb);
    k_scatter<<<512, 256, 0, stream>>>(ei, E, cursor, csr_src);
    k_layer1<<<(N + 3) / 4, 256, 0, stream>>>(h1, a_s1, a_d1, offs, csr_src, b1, amax1, N,
                                              res, rwb, rb, out, w2t, as2, ad2, h2, a_s2, a_d2, amax2);
    k_tail<<<(N + 3) / 4, 256, 0, stream>>>(h2, a_s2, a_d2, offs, csr_src, b2, lnw, lnb,
                                            amax2, out, N);
}

// Round 10
// 335.347 us; speedup vs baseline: 2.2973x; 2.2973x over previous
//
#include <hip/hip_runtime.h>
#include <hip/hip_bf16.h>
#include <math.h>

#define LEAKY_SLOPE 0.2f
#define LN_EPS 1e-5f

typedef __attribute__((ext_vector_type(4))) float f32x4;
typedef __attribute__((ext_vector_type(8))) short short8;

__device__ __forceinline__ float leaky_relu(float x) { return x >= 0.f ? x : LEAKY_SLOPE * x; }
__device__ __forceinline__ float elu1(float x) { return x > 0.f ? x : expm1f(x); }
__device__ __forceinline__ short f2bf(float f) {
    union { __hip_bfloat16 b; short s; } u;
    u.b = __float2bfloat16(f);
    return u.s;
}
__device__ __forceinline__ float bflo(unsigned u) { union { unsigned i; float f; } x; x.i = u << 16; return x.f; }
__device__ __forceinline__ float bfhi(unsigned u) { union { unsigned i; float f; } x; x.i = u & 0xffff0000u; return x.f; }
__device__ __forceinline__ float sbf(short s) { union { unsigned i; float f; } x; x.i = ((unsigned)(unsigned short)s) << 16; return x.f; }
// monotone float<->uint key for atomicMax on floats
__device__ __forceinline__ unsigned fkey(float f) {
    unsigned b = __float_as_uint(f);
    return b ^ (unsigned)(((int)b >> 31) | 0x80000000);
}
__device__ __forceinline__ float funkey(unsigned k) {
    unsigned b = (k & 0x80000000u) ? (k ^ 0x80000000u) : ~k;
    return __uint_as_float(b);
}

// ---------------------------------------------------------------------------
// Per-block int64-vs-int32 edge layout detection (first 64 high words).
#define DETECT_IS64(ei, E)                                              \
    __shared__ int s_is64;                                              \
    {                                                                   \
        if (threadIdx.x < 64) {                                         \
            int v = (threadIdx.x < (E)) ? ((const int*)(ei))[2 * threadIdx.x + 1] : 0; \
            unsigned long long b = __ballot(v != 0);                    \
            if (threadIdx.x == 0) s_is64 = (b == 0ULL);                 \
        }                                                               \
        __syncthreads();                                                \
    }

// ---------------------------------------------------------------------------
// K1 (fat): blocks [0,nbG): h1 = bf16(x @ W1) + fused att scalars + amax.
//           blocks [nbG,nbG+DEGB): in-degree histogram; block nbG also
//           pre-converts resW to bf16 MFMA-fragment order (rwb, 8KB).
#define SUBW1 130
#define DEGB 512
__global__ __launch_bounds__(256) void k_fat1(
    const float* __restrict__ x, const float* __restrict__ W1,
    const float* __restrict__ att_s, const float* __restrict__ att_d,
    short* __restrict__ h1, float* __restrict__ a_src, float* __restrict__ a_dst,
    unsigned* __restrict__ amax, int N,
    const void* __restrict__ ei, int E, int* __restrict__ deg,
    const float* __restrict__ resW, short* __restrict__ rwb, int nbG)
{
    if ((int)blockIdx.x >= nbG) {
        const int b0 = (int)blockIdx.x - nbG;
        if (b0 == 0) {
            // resW -> bf16 fragment table: frag f=kk*4+nc, lane l, elem j
            for (int idx = threadIdx.x; idx < 4096; idx += 256) {
                int f = idx >> 9, lane = (idx >> 3) & 63, j = idx & 7;
                int kk = f >> 2, nc = f & 3;
                int k = kk * 32 + (lane >> 4) * 8 + j;
                int col = nc * 16 + (lane & 15);
                rwb[idx] = f2bf(resW[k * 64 + col]);
            }
        }
        DETECT_IS64(ei, E)
        const int is64 = s_is64;
        for (int e = b0 * 256 + threadIdx.x; e < E; e += DEGB * 256) {
            int d = is64 ? (int)((const long long*)ei)[(size_t)E + e] : ((const int*)ei)[(size_t)E + e];
            atomicAdd(&deg[d], 1);
        }
        return;
    }
    __shared__ short WT[16 * SUBW1 * 8];
    __shared__ float sb[64 * 4];  // per-node {s_h0, s_h1, d_h0, d_h1}
    __shared__ float wm[8];
    const int t = threadIdx.x;
    const int w = t >> 6, l = t & 63, lr = l & 15, lk = l >> 4;
    const int n0 = blockIdx.x * 64;
    for (int idx = t; idx < 16384; idx += 256) {
        int k = idx >> 7, col = idx & 127;
        WT[((k >> 3) * SUBW1 + col) * 8 + (k & 7)] = f2bf(W1[idx]);
    }
    sb[t] = 0.f;
    __syncthreads();

    f32x4 acc[4][2];
    #pragma unroll
    for (int mt = 0; mt < 4; ++mt)
        #pragma unroll
        for (int nt = 0; nt < 2; ++nt) acc[mt][nt] = (f32x4){0.f, 0.f, 0.f, 0.f};

    #pragma unroll
    for (int ks = 0; ks < 4; ++ks) {
        short8 bfr[2];
        #pragma unroll
        for (int nt = 0; nt < 2; ++nt) {
            int col = w * 32 + nt * 16 + lr;
            int kk = ks * 4 + lk;
            bfr[nt] = *(const short8*)&WT[(kk * SUBW1 + col) * 8];
        }
        #pragma unroll
        for (int mt = 0; mt < 4; ++mt) {
            int row = n0 + mt * 16 + lr; if (row >= N) row = N - 1;
            const float* ap = x + (size_t)row * 128 + ks * 32 + lk * 8;
            float4 u0 = *(const float4*)ap;
            float4 u1 = *(const float4*)(ap + 4);
            short8 af;
            af[0] = f2bf(u0.x); af[1] = f2bf(u0.y); af[2] = f2bf(u0.z); af[3] = f2bf(u0.w);
            af[4] = f2bf(u1.x); af[5] = f2bf(u1.y); af[6] = f2bf(u1.z); af[7] = f2bf(u1.w);
            acc[mt][0] = __builtin_amdgcn_mfma_f32_16x16x32_bf16(af, bfr[0], acc[mt][0], 0, 0, 0);
            acc[mt][1] = __builtin_amdgcn_mfma_f32_16x16x32_bf16(af, bfr[1], acc[mt][1], 0, 0, 0);
        }
    }

    const int head = w >> 1;
    float asv[2], adv[2];
    #pragma unroll
    for (int nt = 0; nt < 2; ++nt) {
        int ci = (w & 1) * 32 + nt * 16 + lr;
        asv[nt] = att_s[head * 64 + ci];
        adv[nt] = att_d[head * 64 + ci];
    }
    #pragma unroll
    for (int mt = 0; mt < 4; ++mt) {
        #pragma unroll
        for (int i = 0; i < 4; ++i) {
            float ps = acc[mt][0][i] * asv[0] + acc[mt][1][i] * asv[1];
            float pd = acc[mt][0][i] * adv[0] + acc[mt][1][i] * adv[1];
            #pragma unroll
            for (int o = 1; o < 16; o <<= 1) { ps += __shfl_xor(ps, o); pd += __shfl_xor(pd, o); }
            int rl = mt * 16 + lk * 4 + i;
            if (lr == 0) {
                atomicAdd(&sb[rl * 4 + head], ps);
                atomicAdd(&sb[rl * 4 + 2 + head], pd);
            }
            int row = n0 + rl;
            if (row < N) {
                h1[(size_t)row * 128 + w * 32 + lr]      = f2bf(acc[mt][0][i]);
                h1[(size_t)row * 128 + w * 32 + 16 + lr] = f2bf(acc[mt][1][i]);
            }
        }
    }
    __syncthreads();
    int nl = t >> 2, q = t & 3, n = n0 + nl;
    float v = sb[t];
    bool ok = (n < N);
    if (ok) {
        if (q == 0) a_src[n * 2 + 0] = v;
        else if (q == 1) a_src[n * 2 + 1] = v;
        else if (q == 2) a_dst[n * 2 + 0] = v;
        else a_dst[n * 2 + 1] = v;
    }
    float m0 = (ok && q == 0) ? v : -1e30f;
    float m1 = (ok && q == 1) ? v : -1e30f;
    #pragma unroll
    for (int o = 32; o; o >>= 1) { m0 = fmaxf(m0, __shfl_xor(m0, o)); m1 = fmaxf(m1, __shfl_xor(m1, o)); }
    if (l == 0) { wm[w] = m0; wm[4 + w] = m1; }
    __syncthreads();
    if (t == 0) {
        float M0 = fmaxf(fmaxf(wm[0], wm[1]), fmaxf(wm[2], wm[3]));
        float M1 = fmaxf(fmaxf(wm[4], wm[5]), fmaxf(wm[6], wm[7]));
        atomicMax(&amax[0], fkey(M0));
        atomicMax(&amax[1], fkey(M1));
    }
}

// K3a: per-1024-chunk sums.
__global__ __launch_bounds__(256) void k_bsum(const int* __restrict__ deg, int* __restrict__ bsum, int n)
{
    __shared__ int ws[4];
    const int base = blockIdx.x * 1024;
    int s = 0;
    for (int j = threadIdx.x; j < 1024; j += 256) {
        int i = base + j;
        s += (i < n) ? deg[i] : 0;
    }
    #pragma unroll
    for (int o = 32; o; o >>= 1) s += __shfl_down(s, o);
    if ((threadIdx.x & 63) == 0) ws[threadIdx.x >> 6] = s;
    __syncthreads();
    if (threadIdx.x == 0) bsum[blockIdx.x] = ws[0] + ws[1] + ws[2] + ws[3];
}

// K3c: chunk-base (wave-0 sum of bsum[0..bid)) + local scan -> offs, cursor.
__global__ __launch_bounds__(1024) void k_scan3(const int* __restrict__ deg, const int* __restrict__ bsum,
                                                int* __restrict__ offs, int* __restrict__ cursor,
                                                int n, int nb)
{
    __shared__ int ws[16];
    __shared__ int bb;
    const int i = blockIdx.x * 1024 + threadIdx.x;
    const int l = threadIdx.x & 63, w = threadIdx.x >> 6;
    if (threadIdx.x < 64) {
        int v = 0;
        for (int b = l; b < (int)blockIdx.x; b += 64) v += (b < nb) ? bsum[b] : 0;
        #pragma unroll
        for (int o = 32; o; o >>= 1) v += __shfl_xor(v, o);
        if (l == 0) bb = v;
    }
    int v = (i < n) ? deg[i] : 0;
    int x = v;
    #pragma unroll
    for (int o = 1; o < 64; o <<= 1) { int y = __shfl_up(x, o); if (l >= o) x += y; }
    if (l == 63) ws[w] = x;
    __syncthreads();
    if (threadIdx.x < 16) {
        int s = ws[threadIdx.x];
        #pragma unroll
        for (int o = 1; o < 16; o <<= 1) { int y = __shfl_up(s, o); if (threadIdx.x >= o) s += y; }
        ws[threadIdx.x] = s;
    }
    __syncthreads();
    int add = (w ? ws[w - 1] : 0) + bb;
    if (i < n) {
        offs[i + 1] = x + add;
        cursor[i] = x + add - v;
    }
    if (blockIdx.x == 0 && threadIdx.x == 0) offs[0] = 0;
}

// K4: scatter edges into CSR (by destination).
__global__ __launch_bounds__(256) void k_scatter(const void* __restrict__ ei, int E,
                                                 int* __restrict__ cursor, int* __restrict__ csr_src)
{
    DETECT_IS64(ei, E)
    const int is64 = s_is64;
    for (int e = blockIdx.x * blockDim.x + threadIdx.x; e < E; e += gridDim.x * blockDim.x) {
        int s, d;
        if (is64) {
            const long long* p = (const long long*)ei;
            s = (int)p[e]; d = (int)p[(size_t)E + e];
        } else {
            const int* p = (const int*)ei;
            s = p[e]; d = p[(size_t)E + e];
        }
        int pos = atomicAdd(&cursor[d], 1);
        csr_src[pos] = s;
    }
}

// ---------------------------------------------------------------------------
// K5: layer-1 single-pass softmax+gather (latency-bound), then the SAME WAVE
// streams its node's res-GEMM + right-half out write (BW-bound).
__global__ __launch_bounds__(256) void k_layer1(
    const short* __restrict__ h1, const float* __restrict__ a_s, const float* __restrict__ a_d,
    const int* __restrict__ offs, const int* __restrict__ csr,
    const float* __restrict__ b1, const unsigned* __restrict__ amax,
    short* __restrict__ h1a, int N,
    const float* __restrict__ res, const short* __restrict__ rwb,
    const float* __restrict__ resb, float* __restrict__ out)
{
    const int w = threadIdx.x >> 6, l = threadIdx.x & 63;
    const int n = blockIdx.x * 4 + w;
    if (n >= N) return;
    const float2 adp = *(const float2*)&a_d[2 * n];
    const float2 asp = *(const float2*)&a_s[2 * n];
    const float C0 = leaky_relu(funkey(amax[0]) + adp.x);
    const float C1 = leaky_relu(funkey(amax[1]) + adp.y);
    const float es0 = leaky_relu(asp.x + adp.x) - C0;
    const float es1 = leaky_relu(asp.y + adp.y) - C1;
    const int hsel = l >> 5;
    const int o0 = offs[n], o1 = offs[n + 1];

    float den0 = 0.f, den1 = 0.f;
    float cl0 = 0.f, ch0 = 0.f, cl1 = 0.f, ch1 = 0.f;
    float cl2 = 0.f, ch2 = 0.f, cl3 = 0.f, ch3 = 0.f;
    for (int base = o0; base < o1; base += 64) {
        const int cnt = min(64, o1 - base);
        int sidx = 0; float p0 = 0.f, p1 = 0.f;
        if (l < cnt) {
            sidx = csr[base + l];
            float2 av = *(const float2*)&a_s[2 * sidx];
            p0 = __expf(leaky_relu(av.x + adp.x) - C0);
            p1 = __expf(leaky_relu(av.y + adp.y) - C1);
        }
        den0 += p0; den1 += p1;
        int j = 0;
        for (; j + 4 <= cnt; j += 4) {
            int s0 = __shfl(sidx, j),     s1 = __shfl(sidx, j + 1);
            int s2 = __shfl(sidx, j + 2), s3 = __shfl(sidx, j + 3);
            float q00 = __shfl(p0, j),     q10 = __shfl(p1, j);
            float q01 = __shfl(p0, j + 1), q11 = __shfl(p1, j + 1);
            float q02 = __shfl(p0, j + 2), q12 = __shfl(p1, j + 2);
            float q03 = __shfl(p0, j + 3), q13 = __shfl(p1, j + 3);
            unsigned u0 = *(const unsigned*)(h1 + (size_t)s0 * 128 + 2 * l);
            unsigned u1 = *(const unsigned*)(h1 + (size_t)s1 * 128 + 2 * l);
            unsigned u2 = *(const unsigned*)(h1 + (size_t)s2 * 128 + 2 * l);
            unsigned u3 = *(const unsigned*)(h1 + (size_t)s3 * 128 + 2 * l);
            float w0 = hsel ? q10 : q00, w1 = hsel ? q11 : q01;
            float w2 = hsel ? q12 : q02, w3 = hsel ? q13 : q03;
            cl0 += w0 * bflo(u0); ch0 += w0 * bfhi(u0);
            cl1 += w1 * bflo(u1); ch1 += w1 * bfhi(u1);
            cl2 += w2 * bflo(u2); ch2 += w2 * bfhi(u2);
            cl3 += w3 * bflo(u3); ch3 += w3 * bfhi(u3);
        }
        for (; j < cnt; ++j) {
            int sa = __shfl(sidx, j);
            float qa0 = __shfl(p0, j), qa1 = __shfl(p1, j);
            unsigned ua = *(const unsigned*)(h1 + (size_t)sa * 128 + 2 * l);
            float wa = hsel ? qa1 : qa0;
            cl0 += wa * bflo(ua); ch0 += wa * bfhi(ua);
        }
    }
    #pragma unroll
    for (int o = 32; o; o >>= 1) { den0 += __shfl_xor(den0, o); den1 += __shfl_xor(den1, o); }
    const float psf0 = __expf(es0), psf1 = __expf(es1);
    const float inv0 = 1.f / (den0 + psf0), inv1 = 1.f / (den1 + psf1);

    unsigned us = *(const unsigned*)(h1 + (size_t)n * 128 + 2 * l);
    const float psf = hsel ? psf1 : psf0;
    float acc0 = cl0 + cl1 + cl2 + cl3 + psf * bflo(us);
    float acc1 = ch0 + ch1 + ch2 + ch3 + psf * bfhi(us);
    const float invh = hsel ? inv1 : inv0;
    float2 bv = *(const float2*)&b1[2 * l];
    float v0 = elu1(acc0 * invh + bv.x);
    float v1 = elu1(acc1 * invh + bv.y);
    unsigned up = ((unsigned)(unsigned short)f2bf(v0)) | (((unsigned)(unsigned short)f2bf(v1)) << 16);
    *(unsigned*)(h1a + (size_t)n * 128 + 2 * l) = up;

    __builtin_amdgcn_sched_barrier(0);
    // ---- this node's res_emb = elu(res @ resW + resb) -> out right half ----
    {
        const int lr = l & 15, lk = l >> 4;
        const float* rp = res + (size_t)n * 1024 + lr * 64 + lk * 8;
        const f32x4 f0 = __builtin_nontemporal_load((const f32x4*)(rp));
        const f32x4 f1 = __builtin_nontemporal_load((const f32x4*)(rp + 4));
        const f32x4 f2 = __builtin_nontemporal_load((const f32x4*)(rp + 32));
        const f32x4 f3 = __builtin_nontemporal_load((const f32x4*)(rp + 36));
        short8 fa0, fa1;
        fa0[0] = f2bf(f0[0]); fa0[1] = f2bf(f0[1]); fa0[2] = f2bf(f0[2]); fa0[3] = f2bf(f0[3]);
        fa0[4] = f2bf(f1[0]); fa0[5] = f2bf(f1[1]); fa0[6] = f2bf(f1[2]); fa0[7] = f2bf(f1[3]);
        fa1[0] = f2bf(f2[0]); fa1[1] = f2bf(f2[1]); fa1[2] = f2bf(f2[2]); fa1[3] = f2bf(f2[3]);
        fa1[4] = f2bf(f3[0]); fa1[5] = f2bf(f3[1]); fa1[6] = f2bf(f3[2]); fa1[7] = f2bf(f3[3]);
        const short8* rw8 = (const short8*)rwb;
        float* ob = out + (size_t)n * 2048;
        #pragma unroll
        for (int nc = 0; nc < 4; ++nc) {
            f32x4 a = (f32x4){0.f, 0.f, 0.f, 0.f};
            a = __builtin_amdgcn_mfma_f32_16x16x32_bf16(fa0, rw8[nc * 64 + l], a, 0, 0, 0);
            a = __builtin_amdgcn_mfma_f32_16x16x32_bf16(fa1, rw8[(4 + nc) * 64 + l], a, 0, 0, 0);
            const float rb = resb[nc * 16 + lr];
            #pragma unroll
            for (int ii = 0; ii < 4; ++ii)
                __builtin_nontemporal_store(elu1(a[ii] + rb), ob + (lk * 4 + ii) * 128 + 64 + nc * 16 + lr);
        }
    }
}

// ---------------------------------------------------------------------------
// K6: h2 = bf16(h1a @ W2) [N,64]; fused layer-2 att scalars + global max.
#define SUBW2 66
__global__ __launch_bounds__(256) void k_gemm2m(
    const short* __restrict__ h1a, const float* __restrict__ W2,
    const float* __restrict__ att_s, const float* __restrict__ att_d,
    short* __restrict__ h2, float* __restrict__ a_src, float* __restrict__ a_dst,
    unsigned* __restrict__ amax, int N)
{
    __shared__ short WT[16 * SUBW2 * 8];
    __shared__ float sb[64 * 2];
    __shared__ float wm[4];
    const int t = threadIdx.x;
    const int w = t >> 6, l = t & 63, lr = l & 15, lk = l >> 4;
    const int n0 = blockIdx.x * 64;
    for (int idx = t; idx < 8192; idx += 256) {
        int k = idx >> 6, col = idx & 63;
        WT[((k >> 3) * SUBW2 + col) * 8 + (k & 7)] = f2bf(W2[idx]);
    }
    if (t < 128) sb[t] = 0.f;
    __syncthreads();

    f32x4 acc[4];
    #pragma unroll
    for (int mt = 0; mt < 4; ++mt) acc[mt] = (f32x4){0.f, 0.f, 0.f, 0.f};

    #pragma unroll
    for (int ks = 0; ks < 4; ++ks) {
        short8 bfr = *(const short8*)&WT[((ks * 4 + lk) * SUBW2 + w * 16 + lr) * 8];
        #pragma unroll
        for (int mt = 0; mt < 4; ++mt) {
            int row = n0 + mt * 16 + lr; if (row >= N) row = N - 1;
            short8 af = *(const short8*)(h1a + (size_t)row * 128 + ks * 32 + lk * 8);
            acc[mt] = __builtin_amdgcn_mfma_f32_16x16x32_bf16(af, bfr, acc[mt], 0, 0, 0);
        }
    }

    const float asv = att_s[w * 16 + lr], adv = att_d[w * 16 + lr];
    #pragma unroll
    for (int mt = 0; mt < 4; ++mt) {
        #pragma unroll
        for (int i = 0; i < 4; ++i) {
            float ps = acc[mt][i] * asv;
            float pd = acc[mt][i] * adv;
            #pragma unroll
            for (int o = 1; o < 16; o <<= 1) { ps += __shfl_xor(ps, o); pd += __shfl_xor(pd, o); }
            int rl = mt * 16 + lk * 4 + i;
            if (lr == 0) {
                atomicAdd(&sb[rl * 2 + 0], ps);
                atomicAdd(&sb[rl * 2 + 1], pd);
            }
            int row = n0 + rl;
            if (row < N) h2[(size_t)row * 64 + w * 16 + lr] = f2bf(acc[mt][i]);
        }
    }
    __syncthreads();
    float v = (t < 128) ? sb[t] : -1e30f;
    int n = n0 + (t >> 1);
    bool ok = (t < 128) && (n < N);
    if (ok) {
        if (t & 1) a_dst[n] = v;
        else       a_src[n] = v;
    }
    float m0 = (ok && !(t & 1)) ? v : -1e30f;
    #pragma unroll
    for (int o = 32; o; o >>= 1) m0 = fmaxf(m0, __shfl_xor(m0, o));
    if (l == 0) wm[w] = m0;
    __syncthreads();
    if (t == 0) {
        float M0 = fmaxf(fmaxf(wm[0], wm[1]), fmaxf(wm[2], wm[3]));
        atomicMax(&amax[0], fkey(M0));
    }
}

// ---------------------------------------------------------------------------
// K7: layer-2 single-pass softmax+gather + bias + LayerNorm + broadcast write
// of out's LEFT half. One wave per node.
__global__ __launch_bounds__(256) void k_tail(
    const short* __restrict__ h2, const float* __restrict__ a_s, const float* __restrict__ a_d,
    const int* __restrict__ offs, const int* __restrict__ csr,
    const float* __restrict__ b2, const float* __restrict__ lnw, const float* __restrict__ lnb,
    const unsigned* __restrict__ amax, float* __restrict__ out, int N)
{
    const int w = threadIdx.x >> 6, l = threadIdx.x & 63;
    const int lr = l & 15, lk = l >> 4;
    const int n = blockIdx.x * 4 + w;
    if (n >= N) return;
    const float b2l = b2[l], lnwl = lnw[l], lnbl = lnb[l];
    const float Am = funkey(amax[0]);

    const float adv = a_d[n];
    const float C = leaky_relu(Am + adv);
    const float es = leaky_relu(a_s[n] + adv) - C;
    const int o0 = offs[n], o1 = offs[n + 1];
    float den = 0.f, a0 = 0.f, a1 = 0.f, a2 = 0.f, a3 = 0.f;
    for (int base = o0; base < o1; base += 64) {
        const int cnt = min(64, o1 - base);
        int sidx = 0; float pv = 0.f;
        if (l < cnt) {
            sidx = csr[base + l];
            pv = __expf(leaky_relu(a_s[sidx] + adv) - C);
        }
        den += pv;
        int j = 0;
        for (; j + 4 <= cnt; j += 4) {
            int s0 = __shfl(sidx, j),     s1 = __shfl(sidx, j + 1);
            int s2 = __shfl(sidx, j + 2), s3 = __shfl(sidx, j + 3);
            float q0 = __shfl(pv, j),     q1 = __shfl(pv, j + 1);
            float q2 = __shfl(pv, j + 2), q3 = __shfl(pv, j + 3);
            a0 += q0 * sbf(h2[(size_t)s0 * 64 + l]);
            a1 += q1 * sbf(h2[(size_t)s1 * 64 + l]);
            a2 += q2 * sbf(h2[(size_t)s2 * 64 + l]);
            a3 += q3 * sbf(h2[(size_t)s3 * 64 + l]);
        }
        for (; j < cnt; ++j) {
            int sa = __shfl(sidx, j);
            float qa = __shfl(pv, j);
            a0 += qa * sbf(h2[(size_t)sa * 64 + l]);
        }
    }
    #pragma unroll
    for (int o = 32; o; o >>= 1) den += __shfl_xor(den, o);
    const float psf = __expf(es);
    const float inv = 1.f / (den + psf);
    float o = (a0 + a1 + a2 + a3 + psf * sbf(h2[(size_t)n * 64 + l])) * inv + b2l;
    // ---- LayerNorm across 64 lanes ----
    float mu = o;
    #pragma unroll
    for (int off = 32; off; off >>= 1) mu += __shfl_xor(mu, off);
    mu *= (1.f / 64.f);
    float d = o - mu;
    float vv = d * d;
    #pragma unroll
    for (int off = 32; off; off >>= 1) vv += __shfl_xor(vv, off);
    vv *= (1.f / 64.f);
    const float hl = d * rsqrtf(vv + LN_EPS) * lnwl + lnbl;
    f32x4 hv;
    #pragma unroll
    for (int j = 0; j < 4; ++j) hv[j] = __shfl(hl, lr * 4 + j);
    float* ob = out + (size_t)n * 2048;
    #pragma unroll
    for (int ii = 0; ii < 4; ++ii)
        __builtin_nontemporal_store(hv, (f32x4*)(ob + (lk + 4 * ii) * 128 + lr * 4));
}

// ---------------------------------------------------------------------------
extern "C" void kernel_launch(void* const* d_in, const int* in_sizes, int n_in,
                              void* d_out, int out_size, void* d_ws, size_t ws_size,
                              hipStream_t stream)
{
    const float* x   = (const float*)d_in[0];
    const void*  ei  = d_in[1];
    const float* res = (const float*)d_in[2];
    const float* W1  = (const float*)d_in[3];
    const float* as1 = (const float*)d_in[4];
    const float* ad1 = (const float*)d_in[5];
    const float* b1  = (const float*)d_in[6];
    const float* W2  = (const float*)d_in[7];
    const float* as2 = (const float*)d_in[8];
    const float* ad2 = (const float*)d_in[9];
    const float* b2  = (const float*)d_in[10];
    const float* lnw = (const float*)d_in[11];
    const float* lnb = (const float*)d_in[12];
    const float* rW  = (const float*)d_in[13];
    const float* rb  = (const float*)d_in[14];
    float* out = (float*)d_out;

    const int N = in_sizes[0] / 128;
    const int E = in_sizes[1] / 2;
    const int nb = (N + 1023) / 1024;
    const int nbG = (N + 63) / 64;

    char* base = (char*)d_ws;
    size_t off = 0;
    auto alloc = [&](size_t bytes) -> void* {
        void* p = base + off;
        off = (off + bytes + 255) & ~(size_t)255;
        return p;
    };
    short* h1    = (short*)alloc((size_t)N * 128 * 2);
    short* h1a   = (short*)alloc((size_t)N * 128 * 2);
    short* h2    = (short*)alloc((size_t)N * 64 * 2);
    float* a_s1  = (float*)alloc((size_t)N * 2 * 4);
    float* a_d1  = (float*)alloc((size_t)N * 2 * 4);
    float* a_s2  = (float*)alloc((size_t)N * 4);
    float* a_d2  = (float*)alloc((size_t)N * 4);
    int* deg     = (int*)alloc((size_t)(N + 8) * 4);   // + amax slots
    int* offs    = (int*)alloc((size_t)(N + 1) * 4);
    int* cursor  = (int*)alloc((size_t)N * 4);
    int* csr_src = (int*)alloc((size_t)E * 4);
    int* bsum    = (int*)alloc((size_t)nb * 4);
    short* rwb   = (short*)alloc(4096 * 2);            // resW bf16 fragment table
    unsigned* amax1 = (unsigned*)(deg + N);      // 2 slots (heads)
    unsigned* amax2 = (unsigned*)(deg + N + 2);  // 1 slot

    (void)hipMemsetAsync(deg, 0, (size_t)(N + 8) * 4, stream);
    k_fat1<<<nbG + DEGB, 256, 0, stream>>>(x, W1, as1, ad1, h1, a_s1, a_d1, amax1, N,
                                           ei, E, deg, rW, rwb, nbG);
    k_bsum<<<nb, 256, 0, stream>>>(deg, bsum, N);
    k_scan3<<<nb, 1024, 0, stream>>>(deg, bsum, offs, cursor, N, nb);
    k_scatter<<<512, 256, 0, stream>>>(ei, E, cursor, csr_src);
    k_layer1<<<(N + 3) / 4, 256, 0, stream>>>(h1, a_s1, a_d1, offs, csr_src, b1, amax1, h1a, N,
                                              res, rwb, rb, out);
    k_gemm2m<<<(N + 63) / 64, 256, 0, stream>>>(h1a, W2, as2, ad2, h2, a_s2, a_d2, amax2, N);
    k_tail<<<(N + 3) / 4, 256, 0, stream>>>(h2, a_s2, a_d2, offs, csr_src, b2, lnw, lnb,
                                            amax2, out, N);
}